// Round 7
// baseline (121.211 us; speedup 1.0000x reference)
//
#include <hip/hip_runtime.h>

// FeatureShader: pytorch3d softmax_rgb_blend + TexturesVertex barycentric gather.
// N,H,W,K,C = 4,256,256,8,16.
//
// R9: quad-cooperative gather. R8's two exec-masked gather regions serialize
// on s_waitcnt (no real ILP), and slot-owning threads made one lane do 12
// dependent vfeat loads + 48 FMAs + a 12-exchange reduce-scatter per active
// slot. New mapping: quad == pixel, lane q owns CHANNEL GROUP [4q..4q+3].
// Per pixel, loop s=0..7 over slots: broadcast owner's w_s (quad_perm DPP ->
// quad-uniform predicate, coherent branch); all 4 lanes load that slot's
// faces/bary at the SAME address (TA coalesces to 1 probe/instr); each lane
// loads one float4 per vertex (dep depth 3, FMAs /4) and accumulates its 4
// channels. Reduce-scatter is GONE - lane q already holds out channels
// [4q..4q+3] -> single NT dwordx4 store.
// Kept lessons: exact predicate w > denom*1e-7 (R4: traffic dominates),
// predicated gather only (R7: 5.7x fewer divergent probes), named scalars
// only (R5: arrays -> LDS demotion), DPP softmax reductions, NT streams.

constexpr int CC = 16;

typedef float floatx2 __attribute__((ext_vector_type(2)));
typedef float floatx4 __attribute__((ext_vector_type(4)));
typedef int   intx2   __attribute__((ext_vector_type(2)));

template <int CTRL>
__device__ __forceinline__ int dpp_movi(int x) {
    return __builtin_amdgcn_mov_dpp(x, CTRL, 0xF, 0xF, true);
}
template <int CTRL>
__device__ __forceinline__ float dpp_movf(float x) {
    return __int_as_float(dpp_movi<CTRL>(__float_as_int(x)));
}
#define DPP_XOR1 0xB1          // quad_perm [1,0,3,2]
#define DPP_XOR2 0x4E          // quad_perm [2,3,0,1]
// broadcast from lane o of the quad: ctrl = o * 0x55 (quad_perm [o,o,o,o])

// One slot of the pixel: owner lane OO in quad, slot parity RR.
// All 4 lanes run this; ws/fs are quad-uniform after broadcast.
#define SLOT(OO, RR)                                                         \
    {                                                                        \
        float ws = dpp_movf<(OO) * 0x55>((RR) ? w1 : w0);                    \
        if (ws > thr) {          /* quad-uniform -> coherent branch */       \
            int fs = dpp_movi<(OO) * 0x55>((RR) ? fb : fa);                  \
            int v0 = faces[(size_t)fs * 3 + 0];   /* same addr in quad */    \
            int v1 = faces[(size_t)fs * 3 + 1];                              \
            int v2 = faces[(size_t)fs * 3 + 2];                              \
            const float* bp = bary + (base8 + (OO) * 2 + (RR)) * 3;          \
            float c0 = bp[0] * ws, c1 = bp[1] * ws, c2 = bp[2] * ws;         \
            float4 A0 = vf4[(size_t)v0 * 4 + q];  /* 1 float4/vertex/lane */ \
            float4 A1 = vf4[(size_t)v1 * 4 + q];                             \
            float4 A2 = vf4[(size_t)v2 * 4 + q];                             \
            ax += c0 * A0.x + c1 * A1.x + c2 * A2.x;                         \
            ay += c0 * A0.y + c1 * A1.y + c2 * A2.y;                         \
            az += c0 * A0.z + c1 * A1.z + c2 * A2.z;                         \
            aw += c0 * A0.w + c1 * A1.w + c2 * A2.w;                         \
        }                                                                    \
    }

__global__ __launch_bounds__(256) void feature_shader(
    const float* __restrict__ dists,
    const float* __restrict__ zbuf,
    const float* __restrict__ bary,
    const float* __restrict__ vfeat,
    const float* __restrict__ bg,
    const int*   __restrict__ p2f,
    const int*   __restrict__ faces,
    float* __restrict__ out,
    int n)   // n = N*H*W*K
{
    const float INV_SIGMA = 1e4f;
    const float INV_GAMMA = 1e4f;
    const float EPS       = 1e-10f;
    const float ZFAR      = 100.f;
    const float INV_SPAN  = 1.f / 99.f;

    int u = blockIdx.x * blockDim.x + threadIdx.x;   // (pixel, channel-quad)
    if (u >= (n >> 1)) return;
    int q = threadIdx.x & 3;                         // lane in quad = chan grp
    size_t base8 = (size_t)(u >> 2) * 8;             // pixel's first slot

    // Owner metadata: this lane's dwordx2 covers slots {2u, 2u+1} of its
    // pixel (same stream layout as R8) - coalesced NT loads.
    floatx2 z2 = __builtin_nontemporal_load((const floatx2*)zbuf  + u);
    floatx2 d2 = __builtin_nontemporal_load((const floatx2*)dists + u);
    intx2   f2 = __builtin_nontemporal_load((const intx2*)  p2f   + u);
    int fa = f2.x, fb = f2.y;

    float zinv0 = (fa >= 0) ? (ZFAR - z2.x) * INV_SPAN : 0.f;
    float zinv1 = (fb >= 0) ? (ZFAR - z2.y) * INV_SPAN : 0.f;

    // Pixel max: free in-thread pair max + 2 quad_perm DPP hops.
    float m = fmaxf(zinv0, zinv1);
    m = fmaxf(m, dpp_movf<DPP_XOR1>(m));
    m = fmaxf(m, dpp_movf<DPP_XOR2>(m));
    m = fmaxf(m, EPS);

    float delta = fmaxf(__expf((EPS - m) * INV_GAMMA), EPS);
    float prob0 = (fa >= 0) ? 1.f / (1.f + __expf(d2.x * INV_SIGMA)) : 0.f;
    float prob1 = (fb >= 0) ? 1.f / (1.f + __expf(d2.y * INV_SIGMA)) : 0.f;
    float w0 = prob0 * __expf((zinv0 - m) * INV_GAMMA);
    float w1 = prob1 * __expf((zinv1 - m) * INV_GAMMA);

    // Pixel denominator, same quad-DPP pattern.
    float denom = w0 + w1;
    denom += dpp_movf<DPP_XOR1>(denom);
    denom += dpp_movf<DPP_XOR2>(denom);
    denom += delta;
    float thr = denom * 1e-7f;   // exact predicate (minimal gather set)

    // Accumulator: this lane's 4 channels of the pixel (named scalars).
    float ax = 0.f, ay = 0.f, az = 0.f, aw = 0.f;

    const float4* vf4 = (const float4*)vfeat;

    // 8 slots, unrolled. ws > thr implies f >= 0 (w>0 needs prob>0).
    SLOT(0, 0) SLOT(0, 1)
    SLOT(1, 0) SLOT(1, 1)
    SLOT(2, 0) SLOT(2, 1)
    SLOT(3, 0) SLOT(3, 1)

    // Lane q holds channels [4q..4q+3] -> direct dwordx4 store, no shuffle.
    float4 bgv = ((const float4*)bg)[q];
    float inv_den = 1.f / denom;
    floatx4 o;
    o.x = (ax + delta * bgv.x) * inv_den;
    o.y = (ay + delta * bgv.y) * inv_den;
    o.z = (az + delta * bgv.z) * inv_den;
    o.w = (aw + delta * bgv.w) * inv_den;
    __builtin_nontemporal_store(o, (floatx4*)out + u);   // coalesced dwordx4
}

extern "C" void kernel_launch(void* const* d_in, const int* in_sizes, int n_in,
                              void* d_out, int out_size, void* d_ws, size_t ws_size,
                              hipStream_t stream) {
    const float* dists = (const float*)d_in[0];
    const float* zbuf  = (const float*)d_in[1];
    const float* bary  = (const float*)d_in[2];
    const float* vfeat = (const float*)d_in[3];
    const float* bg    = (const float*)d_in[4];
    const int*   p2f   = (const int*)d_in[5];
    const int*   faces = (const int*)d_in[6];
    float* out = (float*)d_out;

    int n = in_sizes[0];                   // N*H*W*K = 2097152
    int pairs = n >> 1;                    // 1048576 threads
    int block = 256;
    int grid = (pairs + block - 1) / block;  // 4096 blocks

    hipLaunchKernelGGL(feature_shader, dim3(grid), dim3(block), 0, stream,
                       dists, zbuf, bary, vfeat, bg, p2f, faces, out, n);
}